// Round 9
// baseline (283.154 us; speedup 1.0000x reference)
//
#include <hip/hip_runtime.h>

// Aggregator: B=8192, H=10, N=25, F=128, D=256 (half=128). Rows = B*H = 81920.
// out[row][0:128]   = relu(x_self[row]          @ w_self  + bias[0:128])
// out[row][128:256] = relu(mean_n(x_neigh[row]) @ w_neigh + bias[128:256])
//
// R9 = R7 (nt stream + broadcast phase-2, 214.8us) with phase-1 restructured
// so each WAVE streams 4 whole x_neigh rows (51.2 KB) CONTIGUOUSLY:
// 50 x 1KB sequential wave-instructions instead of interleaved 512B segments
// from rows 12.8KB apart. Tests whether HBM row-buffer/granularity is the
// residual 13% gap (5.46 vs ~6.3 TB/s).
// Reduction trick: for idx=64i+lane, fcol=lane&31 is lane-invariant and
// q=2i+(lane>>5) maps statically to (row,n) except i=12,37; cross-half
// combine is one shfl_xor(32) (partner lane has the same fcol).

#define RPB 16  // rows per block (4 waves x 4 rows)

typedef float f32x4 __attribute__((ext_vector_type(4)));

__device__ __forceinline__ f32x4 ntload(const f32x4* p) {
    return __builtin_nontemporal_load(p);
}

__global__ __launch_bounds__(256, 4) void agg_fused_kernel(
    const float* __restrict__ x_self,   // [rows][128]
    const float* __restrict__ x_neigh,  // [rows][25][128]
    const float* __restrict__ w_neigh,  // [128][128]
    const float* __restrict__ w_self,   // [128][128]
    const float* __restrict__ bias,     // [256]
    float* __restrict__ out,            // [rows][256]
    int rows)
{
    __shared__ float xs[RPB][128];
    __shared__ float ag[RPB][128];

    const int tid  = threadIdx.x;
    const int row0 = blockIdx.x * RPB;

    // ---- Phase 1a: x_self rows -> LDS (contiguous 1KB/wave-instr) ----
    {
        const f32x4* xs4 = (const f32x4*)x_self;
        #pragma unroll
        for (int it = 0; it < 2; ++it) {
            const int item = tid + it * 256;
            const int r = item >> 5;
            const int v = item & 31;
            f32x4 s = ntload(&xs4[(size_t)(row0 + r) * 32 + v]);
            *(f32x4*)&xs[r][v * 4] = s;
        }
    }

    // ---- Phase 1b: neighbor mean, wave-contiguous streaming ----
    // Wave wv streams rows row0+4wv .. +3 (51.2 KB contiguous, 50x1KB).
    {
        const int lane = tid & 63;
        const int wv   = tid >> 6;          // wave id 0..3
        const int p    = lane >> 5;         // half: q = 2i + p
        const int fcol = lane & 31;         // this lane's float4 column

        const f32x4* src = (const f32x4*)x_neigh
                         + (size_t)(row0 + wv * 4) * 800 + lane;

        f32x4 acc0 = {0.f, 0.f, 0.f, 0.f};
        f32x4 acc1 = {0.f, 0.f, 0.f, 0.f};
        f32x4 acc2 = {0.f, 0.f, 0.f, 0.f};
        f32x4 acc3 = {0.f, 0.f, 0.f, 0.f};

        // i in [0,12): q=2i+p in 0..23 -> row 0
        #pragma unroll
        for (int i = 0; i < 12; ++i) acc0 += ntload(&src[(size_t)i * 64]);
        // i=12: q=24 (row0,n=24) / q=25 (row1,n=0)
        {
            f32x4 v = ntload(&src[(size_t)12 * 64]);
            if (p == 0) acc0 += v; else acc1 += v;
        }
        // i in [13,25): q in 26..49 -> row 1
        #pragma unroll
        for (int i = 13; i < 25; ++i) acc1 += ntload(&src[(size_t)i * 64]);
        // i in [25,37): q in 50..73 -> row 2
        #pragma unroll
        for (int i = 25; i < 37; ++i) acc2 += ntload(&src[(size_t)i * 64]);
        // i=37: q=74 (row2,n=24) / q=75 (row3,n=0)
        {
            f32x4 v = ntload(&src[(size_t)37 * 64]);
            if (p == 0) acc2 += v; else acc3 += v;
        }
        // i in [38,50): q in 76..99 -> row 3
        #pragma unroll
        for (int i = 38; i < 50; ++i) acc3 += ntload(&src[(size_t)i * 64]);

        // combine halves: partner lane (lane^32) has the same fcol
        const float inv = 1.0f / 25.0f;
        f32x4 m[4] = {acc0, acc1, acc2, acc3};
        #pragma unroll
        for (int r = 0; r < 4; ++r) {
            f32x4 a = m[r];
            a.x += __shfl_xor(a.x, 32, 64);
            a.y += __shfl_xor(a.y, 32, 64);
            a.z += __shfl_xor(a.z, 32, 64);
            a.w += __shfl_xor(a.w, 32, 64);
            a *= inv;
            if (p == 0) *(f32x4*)&ag[wv * 4 + r][fcol * 4] = a;
        }
    }
    __syncthreads();

    // ---- Phase 2: projections (R7 form: scalar weights, broadcast LDS) ----
    const int col = tid & 127;
    const int sel = tid >> 7;
    const float* __restrict__ w = sel ? w_neigh : w_self;
    const float (*vec)[128] = sel ? ag : xs;

    float acc[RPB];
    #pragma unroll
    for (int r = 0; r < RPB; ++r) acc[r] = 0.f;

    for (int f4 = 0; f4 < 32; ++f4) {
        const float w0 = w[(f4 * 4 + 0) * 128 + col];
        const float w1 = w[(f4 * 4 + 1) * 128 + col];
        const float w2 = w[(f4 * 4 + 2) * 128 + col];
        const float w3 = w[(f4 * 4 + 3) * 128 + col];
        #pragma unroll
        for (int r = 0; r < RPB; ++r) {
            float4 v = *(const float4*)&vec[r][f4 * 4];  // wave-uniform broadcast
            acc[r] = fmaf(v.x, w0, acc[r]);
            acc[r] = fmaf(v.y, w1, acc[r]);
            acc[r] = fmaf(v.z, w2, acc[r]);
            acc[r] = fmaf(v.w, w3, acc[r]);
        }
    }

    const float b = bias[sel * 128 + col];
    #pragma unroll
    for (int r = 0; r < RPB; ++r) {
        const float o = fmaxf(acc[r] + b, 0.f);
        __builtin_nontemporal_store(
            o, &out[(size_t)(row0 + r) * 256 + sel * 128 + col]);
    }
}

extern "C" void kernel_launch(void* const* d_in, const int* in_sizes, int n_in,
                              void* d_out, int out_size, void* d_ws, size_t ws_size,
                              hipStream_t stream) {
    const float* x_self  = (const float*)d_in[0];
    const float* x_neigh = (const float*)d_in[1];
    const float* w_neigh = (const float*)d_in[2];
    const float* w_self  = (const float*)d_in[3];
    const float* bias    = (const float*)d_in[4];
    float* out = (float*)d_out;

    const int rows = in_sizes[0] / 128;        // B*H = 81920
    const int blocks = (rows + RPB - 1) / RPB; // 5120

    agg_fused_kernel<<<blocks, 256, 0, stream>>>(
        x_self, x_neigh, w_neigh, w_self, bias, out, rows);
}

// Round 10
// 219.605 us; speedup vs baseline: 1.2894x; 1.2894x over previous
//
#include <hip/hip_runtime.h>

// Aggregator: B=8192, H=10, N=25, F=128, D=256 (half=128). Rows = B*H = 81920.
// out[row][0:128]   = relu(x_self[row]          @ w_self  + bias[0:128])
// out[row][128:256] = relu(mean_n(x_neigh[row]) @ w_neigh + bias[128:256])
//
// R10 = R7 (nt stream, 214.8us) with phase 2 rewritten for v_pk_fma_f32:
// each thread computes 2 cols x 8 rows with f32x2 accumulators via
// __builtin_elementwise_fma -> packed fp32 FMA halves phase-2 VALU instrs
// (2048 scalar fmac -> 1024 pk_fma). VALU/gen was 79% of the HBM share and
// partially non-overlapped (the ~13% residual); packing hides it fully.

#define RPB 16  // rows per block

typedef float f32x4 __attribute__((ext_vector_type(4)));
typedef float f32x2 __attribute__((ext_vector_type(2)));

__device__ __forceinline__ f32x4 ntload(const f32x4* p) {
    return __builtin_nontemporal_load(p);
}

__device__ __forceinline__ f32x2 splat2(float s) {
    f32x2 r; r.x = s; r.y = s; return r;
}

__global__ __launch_bounds__(256, 4) void agg_fused_kernel(
    const float* __restrict__ x_self,   // [rows][128]
    const float* __restrict__ x_neigh,  // [rows][25][128]
    const float* __restrict__ w_neigh,  // [128][128]
    const float* __restrict__ w_self,   // [128][128]
    const float* __restrict__ bias,     // [256]
    float* __restrict__ out,            // [rows][256]
    int rows)
{
    __shared__ float xs[RPB][128];
    __shared__ float ag[RPB][128];

    const int tid  = threadIdx.x;
    const int row0 = blockIdx.x * RPB;

    // ---- Phase 1: stage x_self rows and neighbor-mean rows into LDS ----
    // (byte-identical to R7: nt loads, serial accumulate)
    {
        const f32x4* xs4 = (const f32x4*)x_self;
        const f32x4* xn4 = (const f32x4*)x_neigh;
        #pragma unroll
        for (int it = 0; it < 2; ++it) {
            const int item = tid + it * 256;
            const int r = item >> 5;      // 0..15
            const int v = item & 31;      // float4 column
            const size_t row = (size_t)(row0 + r);

            f32x4 s = ntload(&xs4[row * 32 + v]);
            *(f32x4*)&xs[r][v * 4] = s;

            f32x4 acc = ntload(&xn4[row * 800 + v]);
            const size_t base = row * 800 + v;  // float4 units; row stride 25*32
            #pragma unroll
            for (int n = 1; n < 25; ++n) {
                f32x4 t = ntload(&xn4[base + (size_t)n * 32]);
                acc += t;
            }
            acc *= (1.0f / 25.0f);
            *(f32x4*)&ag[r][v * 4] = acc;
        }
    }
    __syncthreads();

    // ---- Phase 2: projections, 2 cols x 8 rows per thread, packed FMA ----
    // u = tid & 127 -> global col pair c0 = 2u (0..254); sel = u>>6 is
    // wave-uniform (waves 0,2 = self half, waves 1,3 = neigh half).
    // rg = (tid>>7)*8: waves 0,1 do rows 0-7; waves 2,3 do rows 8-15.
    const int u   = tid & 127;
    const int c0  = u * 2;
    const int sel = u >> 6;
    const int rg  = (tid >> 7) * 8;
    const int wc  = c0 & 127;

    const float* __restrict__ w = sel ? w_neigh : w_self;
    const float (*vec)[128] = sel ? ag : xs;

    f32x2 acc[8];
    #pragma unroll
    for (int r = 0; r < 8; ++r) { acc[r].x = 0.f; acc[r].y = 0.f; }

    for (int f4 = 0; f4 < 32; ++f4) {
        // 4 weight rows, f32x2 over col pair: coalesced 512B/wave, L1/L2-hot.
        const f32x2 w0 = *(const f32x2*)&w[(f4 * 4 + 0) * 128 + wc];
        const f32x2 w1 = *(const f32x2*)&w[(f4 * 4 + 1) * 128 + wc];
        const f32x2 w2 = *(const f32x2*)&w[(f4 * 4 + 2) * 128 + wc];
        const f32x2 w3 = *(const f32x2*)&w[(f4 * 4 + 3) * 128 + wc];
        #pragma unroll
        for (int r = 0; r < 8; ++r) {
            // wave-uniform broadcast LDS read (sel, rg, f4 uniform per wave)
            const float4 xv = *(const float4*)&vec[rg + r][f4 * 4];
            acc[r] = __builtin_elementwise_fma(splat2(xv.x), w0, acc[r]);
            acc[r] = __builtin_elementwise_fma(splat2(xv.y), w1, acc[r]);
            acc[r] = __builtin_elementwise_fma(splat2(xv.z), w2, acc[r]);
            acc[r] = __builtin_elementwise_fma(splat2(xv.w), w3, acc[r]);
        }
    }

    const f32x2 b2 = *(const f32x2*)&bias[c0];
    #pragma unroll
    for (int r = 0; r < 8; ++r) {
        f32x2 o;
        o.x = fmaxf(acc[r].x + b2.x, 0.f);
        o.y = fmaxf(acc[r].y + b2.y, 0.f);
        __builtin_nontemporal_store(
            o, (f32x2*)&out[(size_t)(row0 + rg + r) * 256 + c0]);
    }
}

extern "C" void kernel_launch(void* const* d_in, const int* in_sizes, int n_in,
                              void* d_out, int out_size, void* d_ws, size_t ws_size,
                              hipStream_t stream) {
    const float* x_self  = (const float*)d_in[0];
    const float* x_neigh = (const float*)d_in[1];
    const float* w_neigh = (const float*)d_in[2];
    const float* w_self  = (const float*)d_in[3];
    const float* bias    = (const float*)d_in[4];
    float* out = (float*)d_out;

    const int rows = in_sizes[0] / 128;        // B*H = 81920
    const int blocks = (rows + RPB - 1) / RPB; // 5120

    agg_fused_kernel<<<blocks, 256, 0, stream>>>(
        x_self, x_neigh, w_neigh, w_self, bias, out, rows);
}

// Round 11
// 215.135 us; speedup vs baseline: 1.3162x; 1.0208x over previous
//
#include <hip/hip_runtime.h>

// Aggregator: B=8192, H=10, N=25, F=128, D=256 (half=128). Rows = B*H = 81920.
// out[row][0:128]   = relu(x_self[row]          @ w_self  + bias[0:128])
// out[row][128:256] = relu(mean_n(x_neigh[row]) @ w_neigh + bias[128:256])
//
// FINAL (R7 restored, best of 11 variants: 214.8us = 5.46 TB/s effective).
// Key win: __builtin_nontemporal_load/store on the single-use 1GB x_neigh
// stream (+11% vs cached: no L1/L2/L3 allocate-on-miss churn). Weights/bias
// stay cached (only reused data). Phase-2 LDS reads are wave-uniform
// broadcasts (free); compute is fully overlapped with the stream (proven:
// halving FMA instrs via v_pk_fma_f32 was time-neutral, R10).
// Refuted levers: TLP (R1), LDS-traffic cut (R2/R8), cross-tile pipelines
// (R4/R5), pure-stream split (R6), 1KB wave-contiguity (R9), packed FMA (R10).

#define RPB 16  // rows per block

typedef float f32x4 __attribute__((ext_vector_type(4)));

__device__ __forceinline__ f32x4 ntload(const f32x4* p) {
    return __builtin_nontemporal_load(p);
}

__global__ __launch_bounds__(256, 4) void agg_fused_kernel(
    const float* __restrict__ x_self,   // [rows][128]
    const float* __restrict__ x_neigh,  // [rows][25][128]
    const float* __restrict__ w_neigh,  // [128][128]
    const float* __restrict__ w_self,   // [128][128]
    const float* __restrict__ bias,     // [256]
    float* __restrict__ out,            // [rows][256]
    int rows)
{
    __shared__ float xs[RPB][128];
    __shared__ float ag[RPB][128];

    const int tid  = threadIdx.x;
    const int row0 = blockIdx.x * RPB;

    // ---- Phase 1: stage x_self rows and neighbor-mean rows into LDS ----
    // Item space: RPB rows * 32 float4-cols = 512 items; 256 threads * 2 items.
    {
        const f32x4* xs4 = (const f32x4*)x_self;
        const f32x4* xn4 = (const f32x4*)x_neigh;
        #pragma unroll
        for (int it = 0; it < 2; ++it) {
            const int item = tid + it * 256;
            const int r = item >> 5;      // 0..15
            const int v = item & 31;      // float4 column
            const size_t row = (size_t)(row0 + r);

            f32x4 s = ntload(&xs4[row * 32 + v]);
            *(f32x4*)&xs[r][v * 4] = s;

            f32x4 acc = ntload(&xn4[row * 800 + v]);
            const size_t base = row * 800 + v;  // float4 units; row stride 25*32
            #pragma unroll
            for (int n = 1; n < 25; ++n) {
                f32x4 t = ntload(&xn4[base + (size_t)n * 32]);
                acc += t;
            }
            acc *= (1.0f / 25.0f);
            *(f32x4*)&ag[r][v * 4] = acc;
        }
    }
    __syncthreads();

    // ---- Phase 2: projections ----
    // thread t: output column (t & 127), half (t >> 7): 0 = self, 1 = neigh.
    const int col = tid & 127;
    const int sel = tid >> 7;
    const float* __restrict__ w = sel ? w_neigh : w_self;
    const float (*vec)[128] = sel ? ag : xs;

    float acc[RPB];
    #pragma unroll
    for (int r = 0; r < RPB; ++r) acc[r] = 0.f;

    for (int f4 = 0; f4 < 32; ++f4) {
        // 4 weight scalars per iteration; coalesced across the wave (col = lane).
        const float w0 = w[(f4 * 4 + 0) * 128 + col];
        const float w1 = w[(f4 * 4 + 1) * 128 + col];
        const float w2 = w[(f4 * 4 + 2) * 128 + col];
        const float w3 = w[(f4 * 4 + 3) * 128 + col];
        #pragma unroll
        for (int r = 0; r < RPB; ++r) {
            float4 v = *(const float4*)&vec[r][f4 * 4];  // wave-uniform broadcast
            acc[r] = fmaf(v.x, w0, acc[r]);
            acc[r] = fmaf(v.y, w1, acc[r]);
            acc[r] = fmaf(v.z, w2, acc[r]);
            acc[r] = fmaf(v.w, w3, acc[r]);
        }
    }

    const float b = bias[sel * 128 + col];
    #pragma unroll
    for (int r = 0; r < RPB; ++r) {
        const float o = fmaxf(acc[r] + b, 0.f);
        __builtin_nontemporal_store(
            o, &out[(size_t)(row0 + r) * 256 + sel * 128 + col]);
    }
}

extern "C" void kernel_launch(void* const* d_in, const int* in_sizes, int n_in,
                              void* d_out, int out_size, void* d_ws, size_t ws_size,
                              hipStream_t stream) {
    const float* x_self  = (const float*)d_in[0];
    const float* x_neigh = (const float*)d_in[1];
    const float* w_neigh = (const float*)d_in[2];
    const float* w_self  = (const float*)d_in[3];
    const float* bias    = (const float*)d_in[4];
    float* out = (float*)d_out;

    const int rows = in_sizes[0] / 128;        // B*H = 81920
    const int blocks = (rows + RPB - 1) / RPB; // 5120

    agg_fused_kernel<<<blocks, 256, 0, stream>>>(
        x_self, x_neigh, w_neigh, w_self, bias, out, rows);
}